// Round 4
// baseline (782.443 us; speedup 1.0000x reference)
//
#include <hip/hip_runtime.h>
#include <hip/hip_bf16.h>

#define SEQ  2048
#define DH   64
#define NBH  64          // B*H
#define NH   16
#define QT   16          // q-rows per block
#define NW   8           // waves per block
#define NT   (NW * 64)

typedef __attribute__((ext_vector_type(8))) short short8;
typedef __attribute__((ext_vector_type(4))) short short4v;
typedef __attribute__((ext_vector_type(4))) float f32x4;

__device__ __forceinline__ unsigned short f2bf(float x) {
    union { float f; unsigned u; } c; c.f = x;
    return (unsigned short)((c.u + 0x7fffu + ((c.u >> 16) & 1u)) >> 16);
}

// ---- prepass: Q,K fp32 -> bf16 (same layout) ----
__global__ void prep_qk(const float* __restrict__ Q, const float* __restrict__ K,
                        unsigned short* __restrict__ Qb, unsigned short* __restrict__ Kb) {
    unsigned i4 = blockIdx.x * 256u + threadIdx.x;
    const float* src; unsigned short* dst;
    if (i4 < 2097152u) { src = Q; dst = Qb; }
    else { i4 -= 2097152u; src = K; dst = Kb; }
    float4 v = ((const float4*)src)[i4];
    ushort4 o; o.x = f2bf(v.x); o.y = f2bf(v.y); o.z = f2bf(v.z); o.w = f2bf(v.w);
    ((ushort4*)dst)[i4] = o;
}

// ---- prepass: V fp32 [bh][s][d] -> bf16 transposed + kt-pair interleaved ----
// dest pos within 32-chunk: pos = r + 4*kt' + 8*g  <=  src k = r + 16*kt' + 4*g
// so a single short8 at [d][32s + 8*lg] = B-frags (kt=2s, kt=2s+1) for group lg.
__global__ void prep_v(const float* __restrict__ V, unsigned short* __restrict__ VT) {
    __shared__ unsigned short tile[64][72];
    const int t = threadIdx.x;
    const int bh = blockIdx.x >> 5;
    const int s0 = (blockIdx.x & 31) * 64;
    const float* vb = V + ((size_t)bh * SEQ + s0) * DH;
    #pragma unroll
    for (int pp = 0; pp < 4; ++pp) {
        const int sr = pp * 16 + (t >> 4);
        const int dc = (t & 15) * 4;
        float4 v = *(const float4*)(vb + sr * DH + dc);
        tile[sr][dc]     = f2bf(v.x); tile[sr][dc + 1] = f2bf(v.y);
        tile[sr][dc + 2] = f2bf(v.z); tile[sr][dc + 3] = f2bf(v.w);
    }
    __syncthreads();
    const int d = t >> 2, c = (t & 3) * 16;
    short8 w0, w1;
    #pragma unroll
    for (int j = 0; j < 8; ++j) {
        const int p0 = c + j, p1 = c + 8 + j;
        const int s0i = (p0 & 32) + (((p0 >> 2) & 1) << 4) + (((p0 >> 3) & 3) << 2) + (p0 & 3);
        const int s1i = (p1 & 32) + (((p1 >> 2) & 1) << 4) + (((p1 >> 3) & 3) << 2) + (p1 & 3);
        w0[j] = (short)tile[s0i][d];
        w1[j] = (short)tile[s1i][d];
    }
    unsigned short* o = VT + ((size_t)bh * DH + d) * SEQ + s0 + c;
    *(short8*)o = w0; *(short8*)(o + 8) = w1;
}

// ---- prepass: mask int32 -> byte ----
__global__ void prep_m(const int* __restrict__ M, unsigned char* __restrict__ M8) {
    const unsigned i4 = blockIdx.x * 256u + threadIdx.x;
    int4 m = ((const int4*)M)[i4];
    uchar4 o; o.x = (unsigned char)(m.x != 0); o.y = (unsigned char)(m.y != 0);
    o.z = (unsigned char)(m.z != 0); o.w = (unsigned char)(m.w != 0);
    ((uchar4*)M8)[i4] = o;
}

template<bool PRE>
__global__ __launch_bounds__(NT, 4) void attn_main(
    const float* __restrict__ Qf, const float* __restrict__ Kf,
    const float* __restrict__ Vf, const int* __restrict__ Mi,
    const unsigned short* __restrict__ Qb, const unsigned short* __restrict__ Kb,
    const unsigned short* __restrict__ VT, const unsigned char* __restrict__ M8,
    float* __restrict__ O, float* __restrict__ W)
{
    __shared__ float redm[NW * 16], reds[NW * 16], scl[NW * 16];
    __shared__ float part[NW][QT][DH + 4];           // 34.8 KB

    const int tid = threadIdx.x, wv = tid >> 6, ln = tid & 63;
    const int lr = ln & 15, lg = ln >> 4;
    const int bid = blockIdx.x;                      // natural order (head->XCD pinning)
    const int h = bid & 15, t2 = bid >> 4;
    const int qt = t2 & 127, b = t2 >> 7;
    const int bh = b * NH + h, q0 = qt * QT, k0 = wv * (SEQ / NW);

    // ---- Q as MFMA B-fragment (swapped QK^T): lane holds Q[q0+lr][8lg+i] ----
    short8 qf0, qf1;
    if (PRE) {
        const unsigned short* qp = Qb + ((size_t)bh * SEQ + q0 + lr) * DH + 8 * lg;
        qf0 = *(const short8*)qp; qf1 = *(const short8*)(qp + 32);
    } else {
        const float* qp = Qf + ((size_t)bh * SEQ + q0 + lr) * DH + 8 * lg;
        #pragma unroll
        for (int i = 0; i < 8; ++i) { qf0[i] = (short)f2bf(qp[i]); qf1[i] = (short)f2bf(qp[32 + i]); }
    }

    const float SC = 0.18033688011112042f;           // 0.125 * log2(e)

    // ---- scores in registers: p[kt][r] = S[q=lr][k = k0 + 16kt + 4lg + r] (log2 dom) ----
    f32x4 p[16];
    #pragma unroll
    for (int kt = 0; kt < 16; ++kt) {
        short8 ka0, ka1;
        int m0, m1, m2, m3;
        if (PRE) {
            const unsigned short* kp = Kb + ((size_t)bh * SEQ + k0 + kt * 16 + lr) * DH + 8 * lg;
            ka0 = *(const short8*)kp; ka1 = *(const short8*)(kp + 32);
            uchar4 mv = *(const uchar4*)(M8 + (size_t)b * SEQ * SEQ + (size_t)(q0 + lr) * SEQ + k0 + kt * 16 + 4 * lg);
            m0 = mv.x; m1 = mv.y; m2 = mv.z; m3 = mv.w;
        } else {
            const float* kp = Kf + ((size_t)bh * SEQ + k0 + kt * 16 + lr) * DH + 8 * lg;
            #pragma unroll
            for (int i = 0; i < 8; ++i) { ka0[i] = (short)f2bf(kp[i]); ka1[i] = (short)f2bf(kp[32 + i]); }
            int4 mv = *(const int4*)(Mi + (size_t)b * SEQ * SEQ + (size_t)(q0 + lr) * SEQ + k0 + kt * 16 + 4 * lg);
            m0 = mv.x; m1 = mv.y; m2 = mv.z; m3 = mv.w;
        }
        f32x4 a = {0.f, 0.f, 0.f, 0.f};
        a = __builtin_amdgcn_mfma_f32_16x16x32_bf16(ka0, qf0, a, 0, 0, 0);
        a = __builtin_amdgcn_mfma_f32_16x16x32_bf16(ka1, qf1, a, 0, 0, 0);
        p[kt][0] = m0 ? a[0] * SC : -INFINITY;
        p[kt][1] = m1 ? a[1] * SC : -INFINITY;
        p[kt][2] = m2 ? a[2] * SC : -INFINITY;
        p[kt][3] = m3 ? a[3] * SC : -INFINITY;
    }

    // ---- per-wave (local) row max + exp2 + row sum, BEFORE any barrier ----
    float mw = -INFINITY;
    #pragma unroll
    for (int kt = 0; kt < 16; ++kt)
        mw = fmaxf(mw, fmaxf(fmaxf(p[kt][0], p[kt][1]), fmaxf(p[kt][2], p[kt][3])));
    mw = fmaxf(mw, __shfl_xor(mw, 16));
    mw = fmaxf(mw, __shfl_xor(mw, 32));
    mw = fmaxf(mw, -1e30f);                          // guard fully-masked slice
    float ls = 0.f;
    #pragma unroll
    for (int kt = 0; kt < 16; ++kt) {
        #pragma unroll
        for (int r = 0; r < 4; ++r) {
            float e = __builtin_amdgcn_exp2f(p[kt][r] - mw);
            p[kt][r] = e; ls += e;
        }
    }
    ls += __shfl_xor(ls, 16);
    ls += __shfl_xor(ls, 32);
    if (ln < 16) { redm[wv * 16 + ln] = mw; reds[wv * 16 + ln] = ls; }
    __syncthreads();                                 // barrier 1 (only softmax sync)

    // ---- combine wave stats (all lanes, row = lr) ----
    float m = redm[lr];
    #pragma unroll
    for (int w = 1; w < NW; ++w) m = fmaxf(m, redm[w * 16 + lr]);
    float l = 0.f;
    #pragma unroll
    for (int w = 0; w < NW; ++w) l += reds[w * 16 + lr] * __builtin_amdgcn_exp2f(redm[w * 16 + lr] - m);
    const float swv = __builtin_amdgcn_exp2f(mw - m) / l;   // this wave's row scale
    if (ln < 16) scl[wv * 16 + ln] = swv;

    // ---- fused W write + PV (16x16x16 MFMA, A-frag direct from p regs) ----
    f32x4 acc[4] = {{0.f,0.f,0.f,0.f},{0.f,0.f,0.f,0.f},{0.f,0.f,0.f,0.f},{0.f,0.f,0.f,0.f}};
    float* Wr = W + (size_t)bh * SEQ * SEQ + (size_t)(q0 + lr) * SEQ + k0 + 4 * lg;
    const unsigned short* vb = PRE ? (VT + (size_t)bh * DH * SEQ + k0 + 8 * lg) : nullptr;
    #pragma unroll
    for (int s = 0; s < 8; ++s) {
        const int kt0 = 2 * s, kt1 = 2 * s + 1;
        float4 w0, w1;
        w0.x = p[kt0][0] * swv; w0.y = p[kt0][1] * swv;
        w0.z = p[kt0][2] * swv; w0.w = p[kt0][3] * swv;
        w1.x = p[kt1][0] * swv; w1.y = p[kt1][1] * swv;
        w1.z = p[kt1][2] * swv; w1.w = p[kt1][3] * swv;
        *(float4*)(Wr + kt0 * 16) = w0;
        *(float4*)(Wr + kt1 * 16) = w1;
        short4v a0, a1;
        a0[0] = (short)f2bf(p[kt0][0]); a0[1] = (short)f2bf(p[kt0][1]);
        a0[2] = (short)f2bf(p[kt0][2]); a0[3] = (short)f2bf(p[kt0][3]);
        a1[0] = (short)f2bf(p[kt1][0]); a1[1] = (short)f2bf(p[kt1][1]);
        a1[2] = (short)f2bf(p[kt1][2]); a1[3] = (short)f2bf(p[kt1][3]);
        #pragma unroll
        for (int nb = 0; nb < 4; ++nb) {
            short4v blo, bhi;
            if (PRE) {
                short8 u = *(const short8*)(vb + (size_t)(nb * 16 + lr) * SEQ + 32 * s);
                blo[0] = u[0]; blo[1] = u[1]; blo[2] = u[2]; blo[3] = u[3];
                bhi[0] = u[4]; bhi[1] = u[5]; bhi[2] = u[6]; bhi[3] = u[7];
            } else {
                const float* vp = Vf + ((size_t)bh * SEQ + k0 + 32 * s) * DH + nb * 16 + lr;
                #pragma unroll
                for (int i = 0; i < 4; ++i) {
                    blo[i] = (short)f2bf(vp[(4 * lg + i) * DH]);
                    bhi[i] = (short)f2bf(vp[(16 + 4 * lg + i) * DH]);
                }
            }
            acc[nb] = __builtin_amdgcn_mfma_f32_16x16x16bf16_1k(a0, blo, acc[nb], 0, 0, 0);
            acc[nb] = __builtin_amdgcn_mfma_f32_16x16x16bf16_1k(a1, bhi, acc[nb], 0, 0, 0);
        }
    }

    // ---- cross-wave O reduction with per-wave scales ----
    #pragma unroll
    for (int nb = 0; nb < 4; ++nb)
        #pragma unroll
        for (int r = 0; r < 4; ++r)
            part[wv][4 * lg + r][nb * 16 + lr] = acc[nb][r];
    __syncthreads();                                 // barrier 2
    float* Ob = O + ((size_t)bh * SEQ + q0) * DH;
    for (int e = tid; e < QT * DH; e += NT) {
        const int q = e >> 6, d = e & 63;
        float sacc = 0.f;
        #pragma unroll
        for (int w = 0; w < NW; ++w) sacc += part[w][q][d] * scl[w * 16 + q];
        Ob[e] = sacc;
    }
}

extern "C" void kernel_launch(void* const* d_in, const int* in_sizes, int n_in,
                              void* d_out, int out_size, void* d_ws, size_t ws_size,
                              hipStream_t stream) {
    const float* Q = (const float*)d_in[0];
    const float* K = (const float*)d_in[1];
    const float* V = (const float*)d_in[2];
    const int*   M = (const int*)d_in[3];
    float* O = (float*)d_out;
    float* W = O + (size_t)NBH * SEQ * DH;

    const bool pre = ws_size >= (size_t)67108864;   // 64 MiB scratch layout
    unsigned short* Qb = (unsigned short*)d_ws;
    unsigned short* Kb = Qb + (size_t)8388608;
    unsigned short* VT = Qb + (size_t)2 * 8388608;
    unsigned char*  M8 = (unsigned char*)(Qb + (size_t)3 * 8388608);

    if (pre) {
        prep_qk<<<16384, 256, 0, stream>>>(Q, K, Qb, Kb);
        prep_v<<<2048, 256, 0, stream>>>(V, VT);
        prep_m<<<16384, 256, 0, stream>>>(M, M8);
        attn_main<true><<<8192, NT, 0, stream>>>(Q, K, V, M, Qb, Kb, VT, M8, O, W);
    } else {
        attn_main<false><<<8192, NT, 0, stream>>>(Q, K, V, M, nullptr, nullptr, nullptr, nullptr, O, W);
    }
}